// Round 6
// baseline (212.778 us; speedup 1.0000x reference)
//
#include <hip/hip_runtime.h>
#include <cstdint>

// Problem constants (fixed by the reference).
#define B_   16
#define C_   306
#define T_   4096
#define M_   270
#define G_   64     // 8x8 grid, strides {8,1}
#define MT_  17     // m-tiles of 16 (M padded to 272)
#define KB_  10     // k-blocks of 32 (C=306 padded to 320)
#define TT   64     // t per block
#define BDIM 256
#define NW   4

typedef __attribute__((ext_vector_type(8))) short s8;   // 8 bf16 (4 VGPRs) MFMA frag
typedef __attribute__((ext_vector_type(4))) float f4;   // 4 fp32 accumulator
typedef __attribute__((ext_vector_type(4))) int   i4;

// fp32 -> bf16 (RNE) as raw bits; and back.
__device__ __forceinline__ short f2bf(float f) {
    unsigned u = __builtin_bit_cast(unsigned, f);
    u += 0x7FFFu + ((u >> 16) & 1u);
    return (short)(u >> 16);
}
__device__ __forceinline__ float bf2f(short h) {
    return __builtin_bit_cast(float, ((unsigned)(unsigned short)h) << 16);
}

// ---------------------------------------------------------------------------
// A_build: A[b][m][c] = sum_{4 corners} w_k(b,c) * W[m, g_k(b,c)]  (dense fold
// of the scatter matrix into grid_weights: out = (W@S_b) @ x).
// ---------------------------------------------------------------------------
__global__ __launch_bounds__(BDIM) void a_build(const float* __restrict__ pos,
                                                const float* __restrict__ gw,
                                                i4* __restrict__ Ah,
                                                i4* __restrict__ Al) {
    __shared__ float At[16][321];   // k padded to 320; stride 321 -> conflict-free
    const int mt  = blockIdx.x;     // 0..16
    const int b   = blockIdx.y;
    const int tid = threadIdx.x;
    const int mr  = tid & 15;       // m within tile
    const int cg  = tid >> 4;       // c group (16 threads share a c)
    const int m   = mt * 16 + mr;

    for (int c = cg; c < KB_ * 32; c += 16) {
        float v = 0.0f;
        if (c < C_ && m < M_) {
            const float* pp = pos + ((size_t)b * C_ + c) * 2;
            float gp0 = (pp[0] + 1.0f) * 4.0f;
            float gp1 = (pp[1] + 1.0f) * 4.0f;
            float f0 = floorf(gp0), f1 = floorf(gp1);
            int l0 = (int)f0, l1 = (int)f1;
            int h0 = (int)ceilf(gp0), h1 = (int)ceilf(gp1);
            float wh0 = gp0 - f0, wh1 = gp1 - f1;
            float wl0 = 1.0f - wh0, wl1 = 1.0f - wh1;
            const float* wm = gw + (size_t)m * G_;
            v = wl0 * wl1 * wm[l0 * 8 + l1] + wl0 * wh1 * wm[l0 * 8 + h1]
              + wh0 * wl1 * wm[h0 * 8 + l1] + wh0 * wh1 * wm[h0 * 8 + h1];
        }
        At[mr][c] = v;
    }
    __syncthreads();

    const int lane = tid & 63;
    const int mr2  = lane & 15;
    const int j0   = (lane >> 4) * 8;
    for (int kb = tid >> 6; kb < KB_; kb += 4) {
        s8 hv, lv;
        #pragma unroll
        for (int j = 0; j < 8; ++j) {
            float v = At[mr2][kb * 32 + j0 + j];
            short h = f2bf(v);
            hv[j] = h;
            lv[j] = f2bf(v - bf2f(h));
        }
        const int idx = ((b * MT_ + mt) * KB_ + kb) * 64 + lane;
        Ah[idx] = __builtin_bit_cast(i4, hv);
        Al[idx] = __builtin_bit_cast(i4, lv);
    }
}

// ---------------------------------------------------------------------------
// GEMM: out[b] = A_b (272x320) @ x[b] (320x64-tile), bf16x3 MFMA, fp32 accum.
// R6: TEMPLATE change (R3/R4/R5 all ~64-66us inside the per-kb-barrier
// skeleton -> the skeleton, not the schedule, is the stall; m233-class).
// Stage-once-per-half structure, 4 barriers total (was 10):
//   stage half0 (all 40 x loads -> convert -> LDS, 5 kb = 50 KB)
//   issue half1's 40 x loads (latency rides out stream0)
//   BARRIER ; stream half0: 5 kb x 5 mt x 12 MFMA, NO barriers inside
//   BARRIER ; convert+write half1 (loads landed ~3K cy ago: zero exposure)
//   BARRIER ; stream half1 ; epilogue
// Long barrier-free streams let the compiler pipeline A loads / ds_reads /
// MFMAs freely (counted lgkm/vmcnt, nothing blocks hoisting).
// LDS 50 KB -> 2 blocks/CU. T1 XCD swizzle kept (FETCH -19MB, proven).
// ---------------------------------------------------------------------------
__global__ __launch_bounds__(BDIM, 2) void gemm_kernel(
    const float* __restrict__ x, const i4* __restrict__ Ahp,
    const i4* __restrict__ Alp, float* __restrict__ out) {
    __shared__ s8 BhT[5][320];   // [kb-in-half][col*5 + slot], slot q: k=8q..8q+7
    __shared__ s8 BlT[5][320];   // stride 5 slots (80 B); 51,200 B total

    // ---- T1: XCD-aware block swizzle (dispatch-linear id, x fastest) ----
    const int orig = blockIdx.y * gridDim.x + blockIdx.x;
    const int xcd  = orig & 7;            // HW round-robins linear id % 8
    const int nbid = xcd * 128 + (orig >> 3);   // contiguous 128-block chunk/XCD
    const int b    = nbid >> 6;           // 2 consecutive b per XCD
    const int t0   = (nbid & 63) * TT;

    const int tid  = threadIdx.x;
    const int lane = tid & 63;
    const int wave = __builtin_amdgcn_readfirstlane(tid >> 6);
    const int quad = lane >> 4;
    const int lcol = lane & 15;
    const int col  = tid & 63;        // t offset this thread stages

    const float* xrow = x + (size_t)b * C_ * T_ + t0 + col;
    const i4* Abase_h = Ahp + (size_t)(b * MT_ * KB_) * 64 + lane;
    const i4* Abase_l = Alp + (size_t)(b * MT_ * KB_) * 64 + lane;

    // ---- stage half 0: issue ALL 40 loads, then convert (one latency hit) ----
    float rv[5][8];
    #pragma unroll
    for (int k5 = 0; k5 < 5; ++k5)
        #pragma unroll
        for (int j = 0; j < 8; ++j)
            rv[k5][j] = xrow[(size_t)(k5 * 32 + 8 * wave + j) * T_];

    #pragma unroll
    for (int k5 = 0; k5 < 5; ++k5) {
        s8 hv, lv;
        #pragma unroll
        for (int j = 0; j < 8; ++j) {
            short h = f2bf(rv[k5][j]);
            hv[j] = h;
            lv[j] = f2bf(rv[k5][j] - bf2f(h));
        }
        BhT[k5][col * 5 + wave] = hv;   // ds_write_b128, slot-uniform
        BlT[k5][col * 5 + wave] = lv;
    }

    // ---- issue half 1's x loads: latency covered by stream half 0 ----
    float rw[5][8];
    #pragma unroll
    for (int k5 = 0; k5 < 5; ++k5)
        #pragma unroll
        for (int j = 0; j < 8; ++j) {
            const int c0 = 160 + k5 * 32 + 8 * wave + j;
            rw[k5][j] = (c0 < C_) ? xrow[(size_t)c0 * T_] : 0.0f;
        }

    f4 acc[5][4];
    #pragma unroll
    for (int mi = 0; mi < 5; ++mi)
        #pragma unroll
        for (int nt = 0; nt < 4; ++nt)
            acc[mi][nt] = (f4){0.f, 0.f, 0.f, 0.f};

    asm volatile("s_waitcnt lgkmcnt(0)" ::: "memory");
    __builtin_amdgcn_sched_barrier(0);
    __builtin_amdgcn_s_barrier();
    __builtin_amdgcn_sched_barrier(0);

    // ---- stream half 0: barrier-free 5 kb x (17 mt across 4 waves) ----
    #pragma unroll
    for (int k5 = 0; k5 < 5; ++k5) {
        s8 bh[4], bl[4];
        #pragma unroll
        for (int nt = 0; nt < 4; ++nt) {
            bh[nt] = BhT[k5][(nt * 16 + lcol) * 5 + quad];
            bl[nt] = BlT[k5][(nt * 16 + lcol) * 5 + quad];
        }
        #pragma unroll
        for (int mi = 0; mi < 5; ++mi) {
            const int mt = wave + mi * NW;
            if (mt < MT_) {                       // wave-uniform branch
                const int idx = (mt * KB_ + k5) * 64;
                const s8 ah = __builtin_bit_cast(s8, Abase_h[idx]);
                const s8 al = __builtin_bit_cast(s8, Abase_l[idx]);
                #pragma unroll
                for (int nt = 0; nt < 4; ++nt) {
                    f4 a = acc[mi][nt];
                    a = __builtin_amdgcn_mfma_f32_16x16x32_bf16(al, bh[nt], a, 0, 0, 0);
                    a = __builtin_amdgcn_mfma_f32_16x16x32_bf16(ah, bl[nt], a, 0, 0, 0);
                    a = __builtin_amdgcn_mfma_f32_16x16x32_bf16(ah, bh[nt], a, 0, 0, 0);
                    acc[mi][nt] = a;
                }
            }
        }
    }

    asm volatile("s_waitcnt lgkmcnt(0)" ::: "memory");
    __builtin_amdgcn_sched_barrier(0);
    __builtin_amdgcn_s_barrier();
    __builtin_amdgcn_sched_barrier(0);

    // ---- stage half 1: pure VALU+LDS (loads issued one stream ago) ----
    #pragma unroll
    for (int k5 = 0; k5 < 5; ++k5) {
        s8 hv, lv;
        #pragma unroll
        for (int j = 0; j < 8; ++j) {
            short h = f2bf(rw[k5][j]);
            hv[j] = h;
            lv[j] = f2bf(rw[k5][j] - bf2f(h));
        }
        BhT[k5][col * 5 + wave] = hv;
        BlT[k5][col * 5 + wave] = lv;
    }

    asm volatile("s_waitcnt lgkmcnt(0)" ::: "memory");
    __builtin_amdgcn_sched_barrier(0);
    __builtin_amdgcn_s_barrier();
    __builtin_amdgcn_sched_barrier(0);

    // ---- stream half 1 ----
    #pragma unroll
    for (int k5 = 0; k5 < 5; ++k5) {
        s8 bh[4], bl[4];
        #pragma unroll
        for (int nt = 0; nt < 4; ++nt) {
            bh[nt] = BhT[k5][(nt * 16 + lcol) * 5 + quad];
            bl[nt] = BlT[k5][(nt * 16 + lcol) * 5 + quad];
        }
        #pragma unroll
        for (int mi = 0; mi < 5; ++mi) {
            const int mt = wave + mi * NW;
            if (mt < MT_) {
                const int idx = (mt * KB_ + 5 + k5) * 64;
                const s8 ah = __builtin_bit_cast(s8, Abase_h[idx]);
                const s8 al = __builtin_bit_cast(s8, Abase_l[idx]);
                #pragma unroll
                for (int nt = 0; nt < 4; ++nt) {
                    f4 a = acc[mi][nt];
                    a = __builtin_amdgcn_mfma_f32_16x16x32_bf16(al, bh[nt], a, 0, 0, 0);
                    a = __builtin_amdgcn_mfma_f32_16x16x32_bf16(ah, bl[nt], a, 0, 0, 0);
                    a = __builtin_amdgcn_mfma_f32_16x16x32_bf16(ah, bh[nt], a, 0, 0, 0);
                    acc[mi][nt] = a;
                }
            }
        }
    }

    // ---- epilogue: C layout col=lane&15, row=(lane>>4)*4+r (m89-verified) ----
    float* op = out + (size_t)b * M_ * T_ + t0;
    #pragma unroll
    for (int mi = 0; mi < 5; ++mi) {
        const int mt = wave + mi * NW;
        if (mt < MT_) {
            const int mrow = mt * 16 + quad * 4;
            #pragma unroll
            for (int nt = 0; nt < 4; ++nt) {
                #pragma unroll
                for (int r = 0; r < 4; ++r) {
                    const int m = mrow + r;
                    if (m < M_)                    // rows 270/271 are pad
                        op[(size_t)m * T_ + nt * 16 + lcol] = acc[mi][nt][r];
                }
            }
        }
    }
}

extern "C" void kernel_launch(void* const* d_in, const int* in_sizes, int n_in,
                              void* d_out, int out_size, void* d_ws, size_t ws_size,
                              hipStream_t stream) {
    const float* x   = (const float*)d_in[0];
    const float* pos = (const float*)d_in[1];
    const float* gw  = (const float*)d_in[2];
    float* out = (float*)d_out;

    // workspace: Ah 16*17*10*64*16 B = 2,785,280 | Al same  -> ~5.6 MB total
    i4* Ah = (i4*)d_ws;
    i4* Al = (i4*)((char*)d_ws + 2785280);

    a_build<<<dim3(MT_, B_), BDIM, 0, stream>>>(pos, gw, Ah, Al);

    dim3 grid(T_ / TT, B_);
    gemm_kernel<<<grid, BDIM, 0, stream>>>(x, Ah, Al, out);
}

// Round 7
// 190.116 us; speedup vs baseline: 1.1192x; 1.1192x over previous
//
#include <hip/hip_runtime.h>
#include <cstdint>

// Problem constants (fixed by the reference).
#define B_   16
#define C_   306
#define T_   4096
#define M_   270
#define G_   64     // 8x8 grid, strides {8,1}
#define MT_  17     // m-tiles of 16 (M padded to 272)
#define KB_  10     // k-blocks of 32 (C=306 padded to 320)
#define TT   64     // t per block
#define BDIM 256
#define NW   4
#define MIH  3      // max m-tiles per wave (half 0: wave 0 has 3)

typedef __attribute__((ext_vector_type(8))) short s8;   // 8 bf16 (4 VGPRs) MFMA frag
typedef __attribute__((ext_vector_type(4))) float f4;   // 4 fp32 accumulator
typedef __attribute__((ext_vector_type(4))) int   i4;

// fp32 -> bf16 (RNE) as raw bits; and back.
__device__ __forceinline__ short f2bf(float f) {
    unsigned u = __builtin_bit_cast(unsigned, f);
    u += 0x7FFFu + ((u >> 16) & 1u);
    return (short)(u >> 16);
}
__device__ __forceinline__ float bf2f(short h) {
    return __builtin_bit_cast(float, ((unsigned)(unsigned short)h) << 16);
}

// ---------------------------------------------------------------------------
// A_build: A[b][m][c] = sum_{4 corners} w_k(b,c) * W[m, g_k(b,c)]  (dense fold
// of the scatter matrix into grid_weights: out = (W@S_b) @ x).  Unchanged.
// ---------------------------------------------------------------------------
__global__ __launch_bounds__(BDIM) void a_build(const float* __restrict__ pos,
                                                const float* __restrict__ gw,
                                                i4* __restrict__ Ah,
                                                i4* __restrict__ Al) {
    __shared__ float At[16][321];   // k padded to 320; stride 321 -> conflict-free
    const int mt  = blockIdx.x;     // 0..16
    const int b   = blockIdx.y;
    const int tid = threadIdx.x;
    const int mr  = tid & 15;       // m within tile
    const int cg  = tid >> 4;       // c group (16 threads share a c)
    const int m   = mt * 16 + mr;

    for (int c = cg; c < KB_ * 32; c += 16) {
        float v = 0.0f;
        if (c < C_ && m < M_) {
            const float* pp = pos + ((size_t)b * C_ + c) * 2;
            float gp0 = (pp[0] + 1.0f) * 4.0f;
            float gp1 = (pp[1] + 1.0f) * 4.0f;
            float f0 = floorf(gp0), f1 = floorf(gp1);
            int l0 = (int)f0, l1 = (int)f1;
            int h0 = (int)ceilf(gp0), h1 = (int)ceilf(gp1);
            float wh0 = gp0 - f0, wh1 = gp1 - f1;
            float wl0 = 1.0f - wh0, wl1 = 1.0f - wh1;
            const float* wm = gw + (size_t)m * G_;
            v = wl0 * wl1 * wm[l0 * 8 + l1] + wl0 * wh1 * wm[l0 * 8 + h1]
              + wh0 * wl1 * wm[h0 * 8 + l1] + wh0 * wh1 * wm[h0 * 8 + h1];
        }
        At[mr][c] = v;
    }
    __syncthreads();

    const int lane = tid & 63;
    const int mr2  = lane & 15;
    const int j0   = (lane >> 4) * 8;
    for (int kb = tid >> 6; kb < KB_; kb += 4) {
        s8 hv, lv;
        #pragma unroll
        for (int j = 0; j < 8; ++j) {
            float v = At[mr2][kb * 32 + j0 + j];
            short h = f2bf(v);
            hv[j] = h;
            lv[j] = f2bf(v - bf2f(h));
        }
        const int idx = ((b * MT_ + mt) * KB_ + kb) * 64 + lane;
        Ah[idx] = __builtin_bit_cast(i4, hv);
        Al[idx] = __builtin_bit_cast(i4, lv);
    }
}

// ---------------------------------------------------------------------------
// GEMM, R7: occupancy test. R5 template verbatim, but each block does only
// HALF the m-range (mt 0-8 or 9-16) -> acc 80->48 regs, A-dbuf 80->48,
// target ~165/wave with launch_bounds(256,3): 3 waves/SIMD (12/CU, +50% TLP).
// Grid 2048; m-half twins mapped to the SAME XCD (orig and orig+8) so the
// twin's x-tile reads hit that XCD's L2 (x staged twice, fetched ~once).
// R6's template lesson: 94us regression from 40 live prefetch VGPRs ->
// reverted to per-kb phases; registers are the binding resource.
// ---------------------------------------------------------------------------
__global__ __launch_bounds__(BDIM, 3) void gemm_kernel(
    const float* __restrict__ x, const i4* __restrict__ Ahp,
    const i4* __restrict__ Alp, float* __restrict__ out) {
    __shared__ s8 BhT[2][320];   // [buf][col*5 + slot], slot q holds k=8q..8q+7
    __shared__ s8 BlT[2][320];   // stride 5 slots (80 B) -> slot-uniform b128

    // ---- T1 + twin-adjacency: xcd = orig&7; q = orig>>3 enumerates work
    //      within the XCD; q even/odd = m-halves of the same (b,t) tile, so
    //      twins are origs o and o+8 -> identical orig%8 -> same XCD. ----
    const int orig = blockIdx.y * gridDim.x + blockIdx.x;   // [0,2048)
    const int xcd  = orig & 7;
    const int nbid = xcd * 256 + (orig >> 3);               // [0,2048)
    const int b    = nbid >> 7;                             // 2 b's per XCD
    const int r    = nbid & 127;
    const int t0   = (r >> 1) * TT;
    const int half = r & 1;
    const int mbase = half * 9;          // half 0: mt 0-8, half 1: mt 9-16
    const int NMT   = half ? 8 : 9;      // local m-tile count

    const int tid  = threadIdx.x;
    const int lane = tid & 63;
    const int wave = __builtin_amdgcn_readfirstlane(tid >> 6);
    const int quad = lane >> 4;
    const int lcol = lane & 15;
    const int col  = tid & 63;        // t offset this thread stages

    const float* xrow = x + (size_t)b * C_ * T_ + t0 + col;
    const i4* Abase_h = Ahp + (size_t)(b * MT_ * KB_) * 64 + lane;
    const i4* Abase_l = Alp + (size_t)(b * MT_ * KB_) * 64 + lane;

    float rv[2][8];                   // x prefetch, depth 2 (static idx only)
    s8 ah[2][MIH], al[2][MIH];        // A prefetch, depth 1 (double buffer)

    // ---- prologue (A first, then x: same ordering discipline as the loop) ----
    #pragma unroll
    for (int mi = 0; mi < MIH; ++mi) {
        const int ml = wave + mi * NW;
        if (ml < NMT) {
            const int mt = mbase + ml;
            ah[0][mi] = __builtin_bit_cast(s8, Abase_h[(mt * KB_) * 64]);
            al[0][mi] = __builtin_bit_cast(s8, Abase_l[(mt * KB_) * 64]);
        }
    }
    #pragma unroll
    for (int j = 0; j < 8; ++j)
        rv[0][j] = xrow[(size_t)(8 * wave + j) * T_];
    #pragma unroll
    for (int j = 0; j < 8; ++j)
        rv[1][j] = xrow[(size_t)(32 + 8 * wave + j) * T_];

    // convert x[0] -> buf 0 (counted vmcnt: x[1] stays in flight)
    {
        s8 hv, lv;
        #pragma unroll
        for (int j = 0; j < 8; ++j) {
            short h = f2bf(rv[0][j]);
            hv[j] = h;
            lv[j] = f2bf(rv[0][j] - bf2f(h));
        }
        BhT[0][col * 5 + wave] = hv;   // ds_write_b128, slot-uniform
        BlT[0][col * 5 + wave] = lv;
    }

    f4 acc[MIH][4];
    #pragma unroll
    for (int mi = 0; mi < MIH; ++mi)
        #pragma unroll
        for (int nt = 0; nt < 4; ++nt)
            acc[mi][nt] = (f4){0.f, 0.f, 0.f, 0.f};

    asm volatile("s_waitcnt lgkmcnt(0)" ::: "memory");
    __builtin_amdgcn_sched_barrier(0);
    __builtin_amdgcn_s_barrier();
    __builtin_amdgcn_sched_barrier(0);

    #pragma unroll
    for (int kb = 0; kb < KB_; ++kb) {
        const int cur = kb & 1;
        const int nxt = cur ^ 1;

        // (a) issue A[kb+1] FIRST (L2-hot; oldest in queue -> MFMA wait cheap)
        if (kb + 1 < KB_) {
            #pragma unroll
            for (int mi = 0; mi < MIH; ++mi) {
                const int ml = wave + mi * NW;
                if (ml < NMT) {
                    const int idx = ((mbase + ml) * KB_ + kb + 1) * 64;
                    ah[nxt][mi] = __builtin_bit_cast(s8, Abase_h[idx]);
                    al[nxt][mi] = __builtin_bit_cast(s8, Abase_l[idx]);
                }
            }
        }

        // (b) issue x[kb+2] into rv[cur] (younger than A[kb+1]: its latency
        //     is NOT drained by next phase's A-wait)
        if (kb + 2 < KB_) {
            #pragma unroll
            for (int j = 0; j < 8; ++j) {
                const int c0 = (kb + 2) * 32 + 8 * wave + j;
                rv[cur][j] = (c0 < C_) ? xrow[(size_t)c0 * T_] : 0.0f;
            }
        }

        // (c) B fragments for this k-block (slot-uniform ds_read_b128)
        s8 bh[4], bl[4];
        #pragma unroll
        for (int nt = 0; nt < 4; ++nt) {
            bh[nt] = BhT[cur][(nt * 16 + lcol) * 5 + quad];
            bl[nt] = BlT[cur][(nt * 16 + lcol) * 5 + quad];
        }

        // (d) bf16x3 MFMAs (A[kb] landed; counted vmcnt leaves prefetch out)
        #pragma unroll
        for (int mi = 0; mi < MIH; ++mi) {
            const int ml = wave + mi * NW;
            if (ml < NMT) {                       // wave-uniform branch
                #pragma unroll
                for (int nt = 0; nt < 4; ++nt) {
                    f4 a = acc[mi][nt];
                    a = __builtin_amdgcn_mfma_f32_16x16x32_bf16(al[cur][mi], bh[nt], a, 0, 0, 0);
                    a = __builtin_amdgcn_mfma_f32_16x16x32_bf16(ah[cur][mi], bl[nt], a, 0, 0, 0);
                    a = __builtin_amdgcn_mfma_f32_16x16x32_bf16(ah[cur][mi], bh[nt], a, 0, 0, 0);
                    acc[mi][nt] = a;
                }
            }
        }

        // (e) convert x[kb+1] (issued 2 phases ago -> full latency cover)
        //     and stage into buf[nxt]
        if (kb + 1 < KB_) {
            s8 hv, lv;
            #pragma unroll
            for (int j = 0; j < 8; ++j) {
                short h = f2bf(rv[nxt][j]);
                hv[j] = h;
                lv[j] = f2bf(rv[nxt][j] - bf2f(h));
            }
            BhT[nxt][col * 5 + wave] = hv;
            BlT[nxt][col * 5 + wave] = lv;

            // (f) drain OWN LDS ops only; globals in flight cross the barrier.
            asm volatile("s_waitcnt lgkmcnt(0)" ::: "memory");
            __builtin_amdgcn_sched_barrier(0);
            __builtin_amdgcn_s_barrier();
            __builtin_amdgcn_sched_barrier(0);
        }
    }

    // ---- epilogue: C layout col=lane&15, row=(lane>>4)*4+r (m89-verified) ----
    float* op = out + (size_t)b * M_ * T_ + t0;
    #pragma unroll
    for (int mi = 0; mi < MIH; ++mi) {
        const int ml = wave + mi * NW;
        if (ml < NMT) {
            const int mrow = (mbase + ml) * 16 + quad * 4;
            #pragma unroll
            for (int nt = 0; nt < 4; ++nt) {
                #pragma unroll
                for (int rr = 0; rr < 4; ++rr) {
                    const int m = mrow + rr;
                    if (m < M_)                    // rows 270/271 are pad
                        op[(size_t)m * T_ + nt * 16 + lcol] = acc[mi][nt][rr];
                }
            }
        }
    }
}

extern "C" void kernel_launch(void* const* d_in, const int* in_sizes, int n_in,
                              void* d_out, int out_size, void* d_ws, size_t ws_size,
                              hipStream_t stream) {
    const float* x   = (const float*)d_in[0];
    const float* pos = (const float*)d_in[1];
    const float* gw  = (const float*)d_in[2];
    float* out = (float*)d_out;

    // workspace: Ah 16*17*10*64*16 B = 2,785,280 | Al same  -> ~5.6 MB total
    i4* Ah = (i4*)d_ws;
    i4* Al = (i4*)((char*)d_ws + 2785280);

    a_build<<<dim3(MT_, B_), BDIM, 0, stream>>>(pos, gw, Ah, Al);

    dim3 grid(128, 16);   // 2048 blocks: (b, t-tile, m-half)
    gemm_kernel<<<grid, BDIM, 0, stream>>>(x, Ah, Al, out);
}